// Round 14
// baseline (64.127 us; speedup 1.0000x reference)
//
#include <hip/hip_runtime.h>
#include <math.h>

#define HDIM 1024
#define INVB (1 << 13)
#define SCH 32      // rows per score chunk
#define SSLOTS 10   // capacity 320 adj rows per b

// ---------------- K1: scores only: e[b][n] = exp(dot(K[n],Wk)), adj rows ----
// grid 64*SSLOTS blocks x 256 threads; chunk = 32 compacted adj rows.
// Self-scan (r12-proven): ballot/prefix over adj, extract our 32-row window.
__global__ __launch_bounds__(256) void k_scoresE(const float* __restrict__ Kmat,
                                                 const int* __restrict__ adj,
                                                 const float* __restrict__ Wk,
                                                 float* __restrict__ e_out) {
    __shared__ int segc[8];
    __shared__ int codeL[SCH];
    int b = blockIdx.x / SSLOTS;
    int chunk = blockIdx.x - b * SSLOTS;
    int tid = threadIdx.x, wave = tid >> 6, lane = tid & 63;
    int gb = b * 512;
    int start = chunk * SCH;

    int r0w = wave * 128;
    int a0p = adj[gb + r0w + lane] != 0;
    int a1p = adj[gb + r0w + 64 + lane] != 0;
    unsigned long long m0 = __ballot(a0p);
    unsigned long long m1 = __ballot(a1p);
    if (lane == 0) {
        segc[wave * 2]     = __popcll(m0);
        segc[wave * 2 + 1] = __popcll(m1);
    }
    __syncthreads();
    int tot = 0;
#pragma unroll
    for (int i = 0; i < 8; ++i) tot += segc[i];
    if (start >= tot) return;
    {
        unsigned long long lt = (1ull << lane) - 1ull;
        int base = 0;
#pragma unroll
        for (int i = 0; i < 8; ++i) if (i < wave * 2) base += segc[i];
        int pos0 = base + __popcll(m0 & lt);
        if (a0p && pos0 >= start && pos0 < start + SCH)
            codeL[pos0 - start] = r0w + lane;
        int base1 = base + __popcll(m0);
        int pos1 = base1 + __popcll(m1 & lt);
        if (a1p && pos1 >= start && pos1 < start + SCH)
            codeL[pos1 - start] = r0w + 64 + lane;
    }
    if (tid < SCH && start + tid >= tot) codeL[tid] = INVB;
    const float4* wk4 = (const float4*)Wk;
    float4 wk0 = wk4[lane], wk1 = wk4[64 + lane],
           wk2 = wk4[128 + lane], wk3 = wk4[192 + lane];
    __syncthreads();

    // 8 rows per wave, two at a time, 8 float4 loads in flight
#pragma unroll
    for (int pp = 0; pp < 4; ++pp) {
        int rr = wave * 8 + pp * 2;
        int c0 = codeL[rr], c1 = codeL[rr + 1];
        int n0 = c0 & 511, n1 = c1 & 511;
        const float4* kq0 = (const float4*)(Kmat + (size_t)(gb + n0) * HDIM);
        const float4* kq1 = (const float4*)(Kmat + (size_t)(gb + n1) * HDIM);
        float4 a0 = kq0[lane],       a1 = kq0[64 + lane],
               a2 = kq0[128 + lane], a3 = kq0[192 + lane];
        float4 d0 = kq1[lane],       d1 = kq1[64 + lane],
               d2 = kq1[128 + lane], d3 = kq1[192 + lane];
        __builtin_amdgcn_sched_barrier(0);

        float s0 = 0.f, s1 = 0.f;
        s0 = fmaf(a0.x, wk0.x, s0); s0 = fmaf(a0.y, wk0.y, s0);
        s0 = fmaf(a0.z, wk0.z, s0); s0 = fmaf(a0.w, wk0.w, s0);
        s0 = fmaf(a1.x, wk1.x, s0); s0 = fmaf(a1.y, wk1.y, s0);
        s0 = fmaf(a1.z, wk1.z, s0); s0 = fmaf(a1.w, wk1.w, s0);
        s0 = fmaf(a2.x, wk2.x, s0); s0 = fmaf(a2.y, wk2.y, s0);
        s0 = fmaf(a2.z, wk2.z, s0); s0 = fmaf(a2.w, wk2.w, s0);
        s0 = fmaf(a3.x, wk3.x, s0); s0 = fmaf(a3.y, wk3.y, s0);
        s0 = fmaf(a3.z, wk3.z, s0); s0 = fmaf(a3.w, wk3.w, s0);
        s1 = fmaf(d0.x, wk0.x, s1); s1 = fmaf(d0.y, wk0.y, s1);
        s1 = fmaf(d0.z, wk0.z, s1); s1 = fmaf(d0.w, wk0.w, s1);
        s1 = fmaf(d1.x, wk1.x, s1); s1 = fmaf(d1.y, wk1.y, s1);
        s1 = fmaf(d1.z, wk1.z, s1); s1 = fmaf(d1.w, wk1.w, s1);
        s1 = fmaf(d2.x, wk2.x, s1); s1 = fmaf(d2.y, wk2.y, s1);
        s1 = fmaf(d2.z, wk2.z, s1); s1 = fmaf(d2.w, wk2.w, s1);
        s1 = fmaf(d3.x, wk3.x, s1); s1 = fmaf(d3.y, wk3.y, s1);
        s1 = fmaf(d3.z, wk3.z, s1); s1 = fmaf(d3.w, wk3.w, s1);

#pragma unroll
        for (int off = 32; off; off >>= 1) {
            s0 += __shfl_xor(s0, off);
            s1 += __shfl_xor(s1, off);
        }
        if (lane == 0) {
            if (!(c0 & INVB)) e_out[gb + n0] = expf(s0);
            if (!(c1 & INVB)) e_out[gb + n1] = expf(s1);
        }
    }
}

// ---------------- K2: denom -> w_out = adj? e/sum : 0, inv[b] ---------------
__global__ __launch_bounds__(512) void k_denom(const float* __restrict__ e,
                                               const int* __restrict__ adj,
                                               float* __restrict__ w_out,
                                               float* __restrict__ invArr) {
    __shared__ float red[8];
    int b = blockIdx.x;
    int tid = threadIdx.x;
    int wave = tid >> 6, lane = tid & 63;
    int idx = b * 512 + tid;

    float ev = adj[idx] ? e[idx] : 0.f;
    float t = ev;
#pragma unroll
    for (int off = 32; off; off >>= 1) t += __shfl_xor(t, off);
    if (lane == 0) red[wave] = t;
    __syncthreads();
    float tot = red[0];
#pragma unroll
    for (int i = 1; i < 8; ++i) tot += red[i];
    float inv = 1.f / tot;
    w_out[idx] = ev * inv;
    if (tid == 0) invArr[b] = inv;
}

// ---------------- K3: direct u: block = (b, h-eighth) -----------------------
// grid 512 blocks x 256 threads. Self-scan adj&(s|o) -> full active list in
// LDS (rows + gated weights from e). Stream 512B h-slices of active V rows,
// 8 rows in parallel (rsub) x 8-deep batches; 8-way LDS combine; write u
// normalized by inv[b]. No partial buffers.
__global__ __launch_bounds__(256) void k_weightv(const float* __restrict__ V,
                                                 const int* __restrict__ adj,
                                                 const int* __restrict__ sm,
                                                 const int* __restrict__ om,
                                                 const float* __restrict__ e,
                                                 const float* __restrict__ invArr,
                                                 float* __restrict__ u0,
                                                 float* __restrict__ u1) {
    __shared__ int segc[8];
    __shared__ int cn[512];
    __shared__ float2 cw[512];
    __shared__ float4 comb[448];   // 7 rsub x 32 slots x 2 arrays
    int b = blockIdx.x >> 3;
    int oct = blockIdx.x & 7;
    int tid = threadIdx.x, wave = tid >> 6, lane = tid & 63;
    int gb = b * 512;

    // ---- scan: full compacted list of adj&(s|o) rows ------------------------
    int r0w = wave * 128;
    int ra = gb + r0w + lane;
    int rb = ra + 64;
    int sa = sm[ra], oa = om[ra];
    int sb = sm[rb], ob = om[rb];
    int pa = (adj[ra] != 0) && ((sa | oa) != 0);
    int pb = (adj[rb] != 0) && ((sb | ob) != 0);
    unsigned long long m0 = __ballot(pa);
    unsigned long long m1 = __ballot(pb);
    if (lane == 0) {
        segc[wave * 2]     = __popcll(m0);
        segc[wave * 2 + 1] = __popcll(m1);
    }
    __syncthreads();
    int tot = 0;
#pragma unroll
    for (int i = 0; i < 8; ++i) tot += segc[i];
    {
        unsigned long long lt = (1ull << lane) - 1ull;
        int base = 0;
#pragma unroll
        for (int i = 0; i < 8; ++i) if (i < wave * 2) base += segc[i];
        if (pa) {
            int pos = base + __popcll(m0 & lt);
            float ev = e[ra];
            cn[pos] = r0w + lane;
            cw[pos] = make_float2(sa ? ev : 0.f, oa ? ev : 0.f);
        }
        int base1 = base + __popcll(m0);
        if (pb) {
            int pos = base1 + __popcll(m1 & lt);
            float ev = e[rb];
            cn[pos] = r0w + 64 + lane;
            cw[pos] = make_float2(sb ? ev : 0.f, ob ? ev : 0.f);
        }
    }
    __syncthreads();
    int cnt64 = (tot + 63) & ~63;
    if (cnt64 > 512) cnt64 = 512;
    if (tid < 64 && tot + tid < cnt64) {
        cn[tot + tid] = 0;
        cw[tot + tid] = make_float2(0.f, 0.f);
    }
    __syncthreads();

    // ---- stream: rsub r handles rows r, r+8, ..., 8-deep batches -----------
    int slot = tid & 31;
    int rsub = tid >> 5;
    const float4* Vb4 = (const float4*)(V + (size_t)gb * HDIM) + oct * 32 + slot;
    float4 a0 = {0.f, 0.f, 0.f, 0.f};
    float4 a1 = {0.f, 0.f, 0.f, 0.f};
    for (int base = 0; base < cnt64; base += 64) {
        int nn[8]; float2 ww[8];
#pragma unroll
        for (int i = 0; i < 8; ++i) {
            int idx = base + i * 8 + rsub;
            nn[i] = cn[idx];
            ww[i] = cw[idx];
        }
        float4 v[8];
#pragma unroll
        for (int i = 0; i < 8; ++i)
            v[i] = Vb4[(size_t)nn[i] * 256];
        __builtin_amdgcn_sched_barrier(0);
#pragma unroll
        for (int i = 0; i < 8; ++i) {
            a0.x = fmaf(ww[i].x, v[i].x, a0.x); a0.y = fmaf(ww[i].x, v[i].y, a0.y);
            a0.z = fmaf(ww[i].x, v[i].z, a0.z); a0.w = fmaf(ww[i].x, v[i].w, a0.w);
            a1.x = fmaf(ww[i].y, v[i].x, a1.x); a1.y = fmaf(ww[i].y, v[i].y, a1.y);
            a1.z = fmaf(ww[i].y, v[i].z, a1.z); a1.w = fmaf(ww[i].y, v[i].w, a1.w);
        }
    }

    // ---- 8-way combine, normalize, write u ---------------------------------
    if (rsub > 0) {
        comb[(rsub - 1) * 32 + slot] = a0;
        comb[224 + (rsub - 1) * 32 + slot] = a1;
    }
    __syncthreads();
    if (rsub == 0) {
#pragma unroll
        for (int i = 0; i < 7; ++i) {
            float4 c0 = comb[i * 32 + slot];
            float4 c1 = comb[224 + i * 32 + slot];
            a0.x += c0.x; a0.y += c0.y; a0.z += c0.z; a0.w += c0.w;
            a1.x += c1.x; a1.y += c1.y; a1.z += c1.z; a1.w += c1.w;
        }
        float iv = invArr[b];
        a0.x *= iv; a0.y *= iv; a0.z *= iv; a0.w *= iv;
        a1.x *= iv; a1.y *= iv; a1.z *= iv; a1.w *= iv;
        size_t o = (size_t)b * HDIM + oct * 128 + slot * 4;
        *(float4*)(u0 + o) = a0;
        *(float4*)(u1 + o) = a1;
    }
}

// ---------------- K4: split-k GEMM partials: pOut[kc][h][b] -----------------
__global__ __launch_bounds__(256) void k_out(const float* __restrict__ u0,
                                             const float* __restrict__ u1,
                                             const float* __restrict__ Wr0,
                                             const float* __restrict__ Wr1,
                                             float* __restrict__ pOut) {
    __shared__ float lds[64 * 128];
    int tid = threadIdx.x;
    int ht = blockIdx.x >> 4;
    int kc = blockIdx.x & 15;
    const float* usrc = (kc < 8) ? u0 : u1;
    const float* wsrc = (kc < 8) ? Wr0 : Wr1;
    int koff = (kc & 7) * 128;
    int h0 = ht * 64;

    {
        int c4 = tid & 31;
        int r2 = tid >> 5;
#pragma unroll
        for (int i = 0; i < 8; ++i) {
            int row = i * 8 + r2;
            float4 v = *(const float4*)(usrc + (size_t)row * HDIM + koff + c4 * 4);
            *(float4*)&lds[row * 128 + ((c4 ^ (row & 7)) << 2)] = v;
        }
    }
    __syncthreads();

    int b = tid & 63;
    int wu = __builtin_amdgcn_readfirstlane(tid >> 6);
    int hbase = h0 + wu * 16;
    const float* wrow = wsrc + (size_t)hbase * HDIM + koff;

    float acc[16];
#pragma unroll
    for (int j = 0; j < 16; ++j) acc[j] = 0.f;

#pragma unroll 4
    for (int k4 = 0; k4 < 32; ++k4) {
        float4 uv = *(float4*)&lds[b * 128 + ((k4 ^ (b & 7)) << 2)];
#pragma unroll
        for (int j = 0; j < 16; ++j) {
            float4 wv = *(const float4*)(wrow + (size_t)j * HDIM + k4 * 4);
            acc[j] = fmaf(uv.x, wv.x, acc[j]);
            acc[j] = fmaf(uv.y, wv.y, acc[j]);
            acc[j] = fmaf(uv.z, wv.z, acc[j]);
            acc[j] = fmaf(uv.w, wv.w, acc[j]);
        }
    }
#pragma unroll
    for (int j = 0; j < 16; ++j)
        pOut[((size_t)kc * HDIM + hbase + j) * 64 + b] = acc[j];
}

// ---------------- K5: reduce 16 k-chunks -> attn_sum[b][h] ------------------
__global__ __launch_bounds__(256) void k_redout(const float* __restrict__ pOut,
                                                float* __restrict__ out1) {
    int tid = threadIdx.x;
    int b = tid & 63;
    int h = blockIdx.x * 4 + (tid >> 6);
    float acc = 0.f;
#pragma unroll
    for (int kc = 0; kc < 16; ++kc)
        acc += pOut[((size_t)kc * HDIM + h) * 64 + b];
    out1[(size_t)b * HDIM + h] = acc;
}

extern "C" void kernel_launch(void* const* d_in, const int* in_sizes, int n_in,
                              void* d_out, int out_size, void* d_ws, size_t ws_size,
                              hipStream_t stream) {
    const float* Kmat  = (const float*)d_in[1];
    const float* V     = (const float*)d_in[2];
    const int*   adj   = (const int*)d_in[3];
    const int*   smask = (const int*)d_in[4];
    const int*   omask = (const int*)d_in[5];
    const float* Watt  = (const float*)d_in[6];
    const float* Wr0   = (const float*)d_in[8];
    const float* Wr1   = (const float*)d_in[9];
    float* out = (float*)d_out;
    float* ws  = (float*)d_ws;

    // ws layout (float offsets)
    float* e    = ws;                    //  64*512       = 32768
    float* inv  = ws + 32768;            //  64 (pad 128)
    float* u0   = ws + 32896;            //  64*1024      = 65536
    float* u1   = ws + 98432;            //  64*1024      = 65536
    float* pOut = ws + 163968;           //  16*1024*64   = 1048576
    const float* Wk = Watt + HDIM;       // second half of W_att

    k_scoresE<<<64 * SSLOTS, 256, 0, stream>>>(Kmat, adj, Wk, e);
    k_denom  <<<        64, 512, 0, stream>>>(e, adj, out, inv);
    k_weightv<<<       512, 256, 0, stream>>>(V, adj, smask, omask, e, inv, u0, u1);
    k_out    <<<       256, 256, 0, stream>>>(u0, u1, Wr0, Wr1, pOut);
    k_redout <<<       256, 256, 0, stream>>>(pOut, out + 32768);
}